// Round 13
// baseline (290.687 us; speedup 1.0000x reference)
//
#include <hip/hip_runtime.h>
#include <math.h>

#define Kk 8
#define Bb 32
#define Cc 3
#define HW 36864          // 192*192
#define HW4 9216          // float4s per plane
#define CHW 110592        // 3*HW
#define CHW4 27648        // float4s per (k,b) image
#define BCHW 3538944      // B*C*HW
#define OUTMAIN 31850496  // 9*BCHW : index tail start in d_out (elements)
#define NCH 36            // chunks per batch (1024 px each)
#define QK 27             // per-k partial slots: spec[c][3] (24) + plain[3]
#define PARTN 7776        // 8*QK*NCH per batch
#define LP 1028           // padded plane slice (floats) in LDS
#define INVVAR 11.11111111111111f
#define EPSf 1e-5f

__device__ __forceinline__ int clampK(int v) { return v < 0 ? 0 : (v > Kk - 1 ? Kk - 1 : v); }
__device__ __forceinline__ float4 ld4(const float* p) { return *reinterpret_cast<const float4*>(p); }
__device__ __forceinline__ void st4(float* p, float4 v) { *reinterpret_cast<float4*>(p) = v; }

// ---------------------------------------------------------------------------
// Kernel 1: recon -> out[0] AND sd = shp*sum_c(apc-img)^2  (round-7 body).
// grid: 1152 x 256, 1 float4/thread.
// ---------------------------------------------------------------------------
__global__ __launch_bounds__(256) void k_pre_fused(
    const float* __restrict__ images, const float* __restrict__ apc,
    const float* __restrict__ shp, const float* __restrict__ zeta,
    const float* __restrict__ back, float* __restrict__ out,
    float* __restrict__ sd)
{
    int gid = blockIdx.x * 256 + threadIdx.x;
    int b = gid / HW4;
    int pix = (gid - b * HW4) * 4;

    float4 img[Cc], bk[Cc], rec[Cc];
#pragma unroll
    for (int c = 0; c < Cc; ++c) {
        img[c] = ld4(images + (size_t)(b * Cc + c) * HW + pix);
        bk[c]  = ld4(back   + (size_t)(b * Cc + c) * HW + pix);
        rec[c] = make_float4(0.f, 0.f, 0.f, 0.f);
    }
    float cum0 = 1.f, cum1 = 1.f, cum2 = 1.f, cum3 = 1.f;

#pragma unroll
    for (int k = 0; k < Kk; ++k) {
        float4 s = ld4(shp + (size_t)(k * Bb + b) * HW + pix);
        float z = zeta[k * Bb + b];
        float x0 = s.x * z, x1 = s.y * z, x2 = s.z * z, x3 = s.w * z;
        float g0 = x0 * cum0, g1 = x1 * cum1, g2 = x2 * cum2, g3 = x3 * cum3;
        float df0 = 0.f, df1 = 0.f, df2 = 0.f, df3 = 0.f;
#pragma unroll
        for (int c = 0; c < Cc; ++c) {
            float4 av = ld4(apc + ((size_t)(k * Bb + b) * Cc + c) * HW + pix);
            float d0 = av.x - img[c].x, d1 = av.y - img[c].y;
            float d2 = av.z - img[c].z, d3 = av.w - img[c].w;
            df0 += d0 * d0; df1 += d1 * d1; df2 += d2 * d2; df3 += d3 * d3;
            rec[c].x += g0 * av.x; rec[c].y += g1 * av.y;
            rec[c].z += g2 * av.z; rec[c].w += g3 * av.w;
        }
        st4(sd + (size_t)(k * Bb + b) * HW + pix,
            make_float4(s.x * df0, s.y * df1, s.z * df2, s.w * df3));
        cum0 *= (1.f - x0); cum1 *= (1.f - x1); cum2 *= (1.f - x2); cum3 *= (1.f - x3);
    }
#pragma unroll
    for (int c = 0; c < Cc; ++c) {
        st4(out + (size_t)(b * Cc + c) * HW + pix,
            make_float4(rec[c].x + cum0 * bk[c].x, rec[c].y + cum1 * bk[c].y,
                        rec[c].z + cum2 * bk[c].z, rec[c].w + cum3 * bk[c].w));
    }
}

// ---------------------------------------------------------------------------
// Head: resolve idx_{t-2} (plain) then idx_{t-1} (spec slice). Unchanged r12.
// ---------------------------------------------------------------------------
__device__ __forceinline__ void run_head(
    const float* __restrict__ pprev, const float* __restrict__ zeta,
    float* idxf, int b, int t, int write_idx, int tid,
    float* sv, int* s_ia, int* s_ib, int* s_mask)
{
    if (tid < 24) {
        int k = tid / 3, comp = tid - k * 3;
        float v = (comp == 2) ? -1e30f : 0.f;
        const float* src = pprev + (size_t)b * PARTN + (size_t)(k * QK + 24 + comp) * NCH;
        for (int j = 0; j < NCH; ++j) {
            float x = src[j];
            v = (comp == 2) ? fmaxf(v, x) : (v + x);
        }
        sv[tid] = v;
    }
    __syncthreads();
    if (tid == 0) {
        float best = -1e30f; int bi = 0;
        for (int k = 0; k < Kk; ++k) {
            float coef = 1.f;
            for (int j = 0; j < t - 2; ++j)
                if (clampK((int)idxf[j * Bb + b]) == k) coef = -1.f;
            float sc = coef * sv[3 * k + 2] * zeta[k * Bb + b] *
                       expf(-0.5f * INVVAR * sv[3 * k + 0] / (sv[3 * k + 1] + EPSf));
            if (sc > best) { best = sc; bi = k; }
        }
        *s_ia = bi;
    }
    __syncthreads();
    int ia = *s_ia;
    if (tid < 24) {
        int k = tid / 3, comp = tid - k * 3;
        float v = (comp == 2) ? -1e30f : 0.f;
        const float* src = pprev + (size_t)b * PARTN + (size_t)(k * QK + ia * 3 + comp) * NCH;
        for (int j = 0; j < NCH; ++j) {
            float x = src[j];
            v = (comp == 2) ? fmaxf(v, x) : (v + x);
        }
        sv[tid] = v;
    }
    __syncthreads();
    if (tid == 0) {
        float best = -1e30f; int bi = 0;
        for (int k = 0; k < Kk; ++k) {
            float coef = 1.f;
            for (int j = 0; j < t - 2; ++j)
                if (clampK((int)idxf[j * Bb + b]) == k) coef = -1.f;
            if (ia == k) coef = -1.f;
            float sc = coef * sv[3 * k + 2] * zeta[k * Bb + b] *
                       expf(-0.5f * INVVAR * sv[3 * k + 0] / (sv[3 * k + 1] + EPSf));
            if (sc > best) { best = sc; bi = k; }
        }
        *s_ib = bi;
        int mask = 0xFF;
        for (int j = 0; j < t - 2; ++j) mask &= ~(1 << clampK((int)idxf[j * Bb + b]));
        mask &= ~(1 << ia); mask &= ~(1 << bi);
        *s_mask = mask;
        if (write_idx) {
            idxf[(t - 2) * Bb + b] = (float)ia;
            idxf[(t - 1) * Bb + b] = (float)bi;
        }
    }
    __syncthreads();
}

// ---------------------------------------------------------------------------
// Kernel 2 (t=0,2,4,6), LDS-staged: stage 8 shp slices full-wave (1KB unique
// per instr), compute P once per pixel into LDS (full-wave P load/store),
// accumulate candidates from LDS. sd stays global (split-wave read is already
// 1KB-unique: two planes per wave). grid: 1152 x 256. LDS ~67KB -> 2 blk/CU.
// ---------------------------------------------------------------------------
__global__ __launch_bounds__(256) void k_spec(
    const float* __restrict__ shp, const float* __restrict__ sd,
    float* __restrict__ Pbuf, float* idxf, const float* __restrict__ zeta,
    const float* __restrict__ pprev, float* __restrict__ pcur, int t)
{
    int b = blockIdx.x / NCH, ch = blockIdx.x % NCH;
    int tid = threadIdx.x;
    int g = tid >> 5, l = tid & 31;
    const int base = ch * 1024;                 // pixel base of this chunk

    __shared__ float sv[24];
    __shared__ int s_ia, s_ib, s_mask;
    __shared__ float lshp[Kk][LP];
    __shared__ float ldsP[LP];

    if (t == 0) {
        if (tid == 0) { s_ia = 0; s_ib = 0; s_mask = 0xFF; }
    } else {
        run_head(pprev, zeta, idxf, b, t, (ch == 0), tid, sv, &s_ia, &s_ib, &s_mask);
    }

    // ---- stage shp slices: full-wave coalesced, 8 x 1KB unique per wave ----
#pragma unroll
    for (int q = 0; q < Kk; ++q) {
        float4 v = ld4(shp + (size_t)(q * Bb + b) * HW + base + tid * 4);
        *reinterpret_cast<float4*>(&lshp[q][tid * 4]) = v;
    }
    __syncthreads();
    int ia = s_ia, ib = s_ib, mask = s_mask;

    // ---- P phase: thread tid owns float4 #tid (full-wave load/store) ----
    if (t > 0) {
        float4 p0 = make_float4(1.f, 1.f, 1.f, 1.f);
        if (t > 2) p0 = ld4(Pbuf + (size_t)b * HW + base + tid * 4);
        float4 sa = *reinterpret_cast<const float4*>(&lshp[ia][tid * 4]);
        float4 sb = *reinterpret_cast<const float4*>(&lshp[ib][tid * 4]);
        float4 p1, P;
        p1.x = p0.x * (1.f - sa.x * p0.x); p1.y = p0.y * (1.f - sa.y * p0.y);
        p1.z = p0.z * (1.f - sa.z * p0.z); p1.w = p0.w * (1.f - sa.w * p0.w);
        P.x = p1.x * (1.f - sb.x * p1.x); P.y = p1.y * (1.f - sb.y * p1.y);
        P.z = p1.z * (1.f - sb.z * p1.z); P.w = p1.w * (1.f - sb.w * p1.w);
        *reinterpret_cast<float4*>(&ldsP[tid * 4]) = P;
        if (t == 2 || t == 4) st4(Pbuf + (size_t)b * HW + base + tid * 4, P);
        __syncthreads();
    }

    // ---- accumulate: group g targets k=g; candidates from LDS ----
    float pd = 0.f, pa = 0.f, pm = -1e30f;
    float accd[Kk], acca[Kk], accm[Kk];
#pragma unroll
    for (int c = 0; c < Kk; ++c) { accd[c] = 0.f; acca[c] = 0.f; accm[c] = -1e30f; }

    for (int i = 0; i < 8; ++i) {
        int f4 = i * 32 + l;                    // float4 index 0..255
        float4 sdg = ld4(sd + (size_t)(g * Bb + b) * HW + base + f4 * 4);
        float4 sg  = *reinterpret_cast<const float4*>(&lshp[g][f4 * 4]);
        float4 P = make_float4(1.f, 1.f, 1.f, 1.f);
        if (t > 0) P = *reinterpret_cast<const float4*>(&ldsP[f4 * 4]);

        float4 sc[Kk];
#pragma unroll
        for (int c = 0; c < Kk; ++c)
            sc[c] = *reinterpret_cast<const float4*>(&lshp[c][f4 * 4]);

#define SPEC_C(c, scv) if (mask & (1 << c)) { \
        float u = 1.f - scv * P_; float tt = m_ * u; \
        acca[c] += tt; accm[c] = fmaxf(accm[c], tt); accd[c] = fmaf(v_, u, accd[c]); }
#define DO_ELEM(e) { float P_ = P.e; float m_ = sg.e * P_; float v_ = sdg.e * P_; \
        pd += v_; pa += m_; pm = fmaxf(pm, m_); \
        SPEC_C(0, sc[0].e) SPEC_C(1, sc[1].e) SPEC_C(2, sc[2].e) SPEC_C(3, sc[3].e) \
        SPEC_C(4, sc[4].e) SPEC_C(5, sc[5].e) SPEC_C(6, sc[6].e) SPEC_C(7, sc[7].e) }
        DO_ELEM(x) DO_ELEM(y) DO_ELEM(z) DO_ELEM(w)
#undef DO_ELEM
#undef SPEC_C
    }

    // ---- LDS tree reduce per 32-lane group (unchanged from r12) ----
    __shared__ float ls[Kk][32][29];
    float* mine = ls[g][l];
#pragma unroll
    for (int c = 0; c < Kk; ++c) {
        mine[c * 3 + 0] = accd[c]; mine[c * 3 + 1] = acca[c]; mine[c * 3 + 2] = accm[c];
    }
    mine[24] = pd; mine[25] = pa; mine[26] = pm;
    __syncthreads();
    for (int st = 16; st > 0; st >>= 1) {
        if (l < st) {
            float* other = ls[g][l + st];
#pragma unroll
            for (int q = 0; q < QK; ++q)
                mine[q] = (q % 3 == 2) ? fmaxf(mine[q], other[q]) : (mine[q] + other[q]);
        }
        __syncthreads();
    }
    if (l == 0) {
#pragma unroll
        for (int q = 0; q < QK; ++q)
            pcur[(size_t)b * PARTN + (size_t)(g * QK + q) * NCH + ch] = mine[q];
    }
}

// ---------------------------------------------------------------------------
// Kernel 3: gather with fused idx6/idx7 resolution. Unchanged from r12.
// grid: 6912 x 256.
// ---------------------------------------------------------------------------
__global__ __launch_bounds__(256) void k_gather(
    const float* __restrict__ apc, const float* __restrict__ partials6,
    const float* __restrict__ zeta, float* idxf, float* __restrict__ out)
{
    int image = blockIdx.x / 27;           // 0..255 == t*32+b
    int chunk = blockIdx.x % 27;
    int t = image >> 5, b = image & 31;
    int tid = threadIdx.x;

    int s;
    if (t >= 6) {
        __shared__ float sv[24];
        __shared__ int s_ia, s_ib, s_mask;
        run_head(partials6, zeta, idxf, b, 8, (t == 6 && chunk == 0), tid,
                 sv, &s_ia, &s_ib, &s_mask);
        s = (t == 6) ? s_ia : s_ib;
    } else {
        s = clampK((int)idxf[t * Bb + b]);
    }

    const float4* src = reinterpret_cast<const float4*>(apc) + (size_t)(s * Bb + b) * CHW4;
    float4* dst = reinterpret_cast<float4*>(out) + (size_t)(image + Bb) * CHW4;
    int base = chunk * 1024 + tid;
    float4 r0 = src[base];
    float4 r1 = src[base + 256];
    float4 r2 = src[base + 512];
    float4 r3 = src[base + 768];
    dst[base]       = r0;
    dst[base + 256] = r1;
    dst[base + 512] = r2;
    dst[base + 768] = r3;
}

// ---------------------------------------------------------------------------
// Round 13: spec de-duplication. r12's g-split made a wave's two halves load
// identical 512B for all 8 candidate shp streams (0.55 path efficiency, 5.4
// B/cy/CU vs the ~10 B/cy wall that gather/red sit at). Fix: stage shp in
// LDS with full-wave 1KB-unique loads; P computed once per pixel into LDS
// (full-wave); candidates read from LDS (broadcast across wave halves).
// Head/partials/tree/pre/gather unchanged from r12 (passed).
// ---------------------------------------------------------------------------
extern "C" void kernel_launch(void* const* d_in, const int* in_sizes, int n_in,
                              void* d_out, int out_size, void* d_ws, size_t ws_size,
                              hipStream_t stream)
{
    const float *images = nullptr, *apc = nullptr, *shp = nullptr;
    const float *zeta = nullptr, *back = nullptr;
    for (int i = 0; i < n_in; ++i) {
        int s = in_sizes[i];
        if (s == 28311552)      apc  = (const float*)d_in[i];
        else if (s == 9437184)  shp  = (const float*)d_in[i];
        else if (s == 256)      zeta = (const float*)d_in[i];
        else if (s == 3538944) {
            if (!images) images = (const float*)d_in[i];
            else         back   = (const float*)d_in[i];
        }
    }
    if (!images || !apc || !shp || !zeta || !back) {   // fallback: dict order
        images = (const float*)d_in[0]; apc = (const float*)d_in[1];
        shp = (const float*)d_in[2]; zeta = (const float*)d_in[3];
        back = (const float*)d_in[4];
    }
    float* out = (float*)d_out;
    float* idxf = out + OUTMAIN;                       // 256-element tail

    // Scratch: sd(9437184) + Pbuf(1179648) + pA(248832) + pB(248832) = 44.5MB
    float* sd = (d_ws != nullptr && ws_size >= (size_t)48 * 1024 * 1024)
                  ? (float*)d_ws
                  : (out + BCHW);    // alias into out[1..8], dead before gather
    float* Pbuf = sd + 9437184;
    float* pA   = Pbuf + 1179648;
    float* pB   = pA + 248832;

    k_pre_fused<<<1152, 256, 0, stream>>>(images, apc, shp, zeta, back, out, sd);
    k_spec<<<1152, 256, 0, stream>>>(shp, sd, Pbuf, idxf, zeta, pB, pA, 0);
    k_spec<<<1152, 256, 0, stream>>>(shp, sd, Pbuf, idxf, zeta, pA, pB, 2);
    k_spec<<<1152, 256, 0, stream>>>(shp, sd, Pbuf, idxf, zeta, pB, pA, 4);
    k_spec<<<1152, 256, 0, stream>>>(shp, sd, Pbuf, idxf, zeta, pA, pB, 6);
    k_gather<<<6912, 256, 0, stream>>>(apc, pB, zeta, idxf, out);
}

// Round 14
// 214.395 us; speedup vs baseline: 1.3559x; 1.3559x over previous
//
#include <hip/hip_runtime.h>
#include <math.h>

#define Kk 8
#define Bb 32
#define Cc 3
#define HW 36864          // 192*192
#define HW4 9216          // float4s per plane
#define CHW 110592        // 3*HW
#define CHW4 27648        // float4s per (k,b) image
#define BCHW 3538944      // B*C*HW
#define OUTMAIN 31850496  // 9*BCHW : index tail start in d_out (elements)
#define NCH 36            // chunks per batch (1024 px each)
#define QK 27             // per-k partial slots: spec[c][3] (24) + plain[3]
#define PARTN 7776        // 8*QK*NCH per batch
#define INVVAR 11.11111111111111f
#define EPSf 1e-5f

__device__ __forceinline__ int clampK(int v) { return v < 0 ? 0 : (v > Kk - 1 ? Kk - 1 : v); }
__device__ __forceinline__ float4 ld4(const float* p) { return *reinterpret_cast<const float4*>(p); }
__device__ __forceinline__ void st4(float* p, float4 v) { *reinterpret_cast<float4*>(p) = v; }

// ---------------------------------------------------------------------------
// Kernel 1: recon -> out[0] AND sd = shp*sum_c(apc-img)^2  (round-7 body).
// grid: 1152 x 256, 1 float4/thread.
// ---------------------------------------------------------------------------
__global__ __launch_bounds__(256) void k_pre_fused(
    const float* __restrict__ images, const float* __restrict__ apc,
    const float* __restrict__ shp, const float* __restrict__ zeta,
    const float* __restrict__ back, float* __restrict__ out,
    float* __restrict__ sd)
{
    int gid = blockIdx.x * 256 + threadIdx.x;
    int b = gid / HW4;
    int pix = (gid - b * HW4) * 4;

    float4 img[Cc], bk[Cc], rec[Cc];
#pragma unroll
    for (int c = 0; c < Cc; ++c) {
        img[c] = ld4(images + (size_t)(b * Cc + c) * HW + pix);
        bk[c]  = ld4(back   + (size_t)(b * Cc + c) * HW + pix);
        rec[c] = make_float4(0.f, 0.f, 0.f, 0.f);
    }
    float cum0 = 1.f, cum1 = 1.f, cum2 = 1.f, cum3 = 1.f;

#pragma unroll
    for (int k = 0; k < Kk; ++k) {
        float4 s = ld4(shp + (size_t)(k * Bb + b) * HW + pix);
        float z = zeta[k * Bb + b];
        float x0 = s.x * z, x1 = s.y * z, x2 = s.z * z, x3 = s.w * z;
        float g0 = x0 * cum0, g1 = x1 * cum1, g2 = x2 * cum2, g3 = x3 * cum3;
        float df0 = 0.f, df1 = 0.f, df2 = 0.f, df3 = 0.f;
#pragma unroll
        for (int c = 0; c < Cc; ++c) {
            float4 av = ld4(apc + ((size_t)(k * Bb + b) * Cc + c) * HW + pix);
            float d0 = av.x - img[c].x, d1 = av.y - img[c].y;
            float d2 = av.z - img[c].z, d3 = av.w - img[c].w;
            df0 += d0 * d0; df1 += d1 * d1; df2 += d2 * d2; df3 += d3 * d3;
            rec[c].x += g0 * av.x; rec[c].y += g1 * av.y;
            rec[c].z += g2 * av.z; rec[c].w += g3 * av.w;
        }
        st4(sd + (size_t)(k * Bb + b) * HW + pix,
            make_float4(s.x * df0, s.y * df1, s.z * df2, s.w * df3));
        cum0 *= (1.f - x0); cum1 *= (1.f - x1); cum2 *= (1.f - x2); cum3 *= (1.f - x3);
    }
#pragma unroll
    for (int c = 0; c < Cc; ++c) {
        st4(out + (size_t)(b * Cc + c) * HW + pix,
            make_float4(rec[c].x + cum0 * bk[c].x, rec[c].y + cum1 * bk[c].y,
                        rec[c].z + cum2 * bk[c].z, rec[c].w + cum3 * bk[c].w));
    }
}

// ---------------------------------------------------------------------------
// Head: resolve idx_{t-2} (plain) then idx_{t-1} (spec slice). Unchanged r12.
// ---------------------------------------------------------------------------
__device__ __forceinline__ void run_head(
    const float* __restrict__ pprev, const float* __restrict__ zeta,
    float* idxf, int b, int t, int write_idx, int tid,
    float* sv, int* s_ia, int* s_ib, int* s_mask)
{
    if (tid < 24) {
        int k = tid / 3, comp = tid - k * 3;
        float v = (comp == 2) ? -1e30f : 0.f;
        const float* src = pprev + (size_t)b * PARTN + (size_t)(k * QK + 24 + comp) * NCH;
        for (int j = 0; j < NCH; ++j) {
            float x = src[j];
            v = (comp == 2) ? fmaxf(v, x) : (v + x);
        }
        sv[tid] = v;
    }
    __syncthreads();
    if (tid == 0) {
        float best = -1e30f; int bi = 0;
        for (int k = 0; k < Kk; ++k) {
            float coef = 1.f;
            for (int j = 0; j < t - 2; ++j)
                if (clampK((int)idxf[j * Bb + b]) == k) coef = -1.f;
            float sc = coef * sv[3 * k + 2] * zeta[k * Bb + b] *
                       expf(-0.5f * INVVAR * sv[3 * k + 0] / (sv[3 * k + 1] + EPSf));
            if (sc > best) { best = sc; bi = k; }
        }
        *s_ia = bi;
    }
    __syncthreads();
    int ia = *s_ia;
    if (tid < 24) {
        int k = tid / 3, comp = tid - k * 3;
        float v = (comp == 2) ? -1e30f : 0.f;
        const float* src = pprev + (size_t)b * PARTN + (size_t)(k * QK + ia * 3 + comp) * NCH;
        for (int j = 0; j < NCH; ++j) {
            float x = src[j];
            v = (comp == 2) ? fmaxf(v, x) : (v + x);
        }
        sv[tid] = v;
    }
    __syncthreads();
    if (tid == 0) {
        float best = -1e30f; int bi = 0;
        for (int k = 0; k < Kk; ++k) {
            float coef = 1.f;
            for (int j = 0; j < t - 2; ++j)
                if (clampK((int)idxf[j * Bb + b]) == k) coef = -1.f;
            if (ia == k) coef = -1.f;
            float sc = coef * sv[3 * k + 2] * zeta[k * Bb + b] *
                       expf(-0.5f * INVVAR * sv[3 * k + 0] / (sv[3 * k + 1] + EPSf));
            if (sc > best) { best = sc; bi = k; }
        }
        *s_ib = bi;
        int mask = 0xFF;
        for (int j = 0; j < t - 2; ++j) mask &= ~(1 << clampK((int)idxf[j * Bb + b]));
        mask &= ~(1 << ia); mask &= ~(1 << bi);
        *s_mask = mask;
        if (write_idx) {
            idxf[(t - 2) * Bb + b] = (float)ia;
            idxf[(t - 1) * Bb + b] = (float)bi;
        }
    }
    __syncthreads();
}

// ---------------------------------------------------------------------------
// Kernel 2 (t=0,2,4,6): r12 body + fused gather copies. After the head
// resolves ia=idx_{t-2}, ib=idx_{t-1}, this block also copies its chunk of
// apc[ia] -> out[t-1] and apc[ib] -> out[t] (do_copy path only): spec kernels
// run far below the memory wall, so the copy rides in their BW slack.
// grid: 1152 x 256. partials: [b][k*27 + (c*3+comp | 24..26 plain)][ch]
// ---------------------------------------------------------------------------
__global__ __launch_bounds__(256, 4) void k_spec(
    const float* __restrict__ shp, const float* __restrict__ sd,
    float* __restrict__ Pbuf, float* idxf, const float* __restrict__ zeta,
    const float* __restrict__ pprev, float* __restrict__ pcur,
    const float* __restrict__ apc, float* __restrict__ gout,
    int t, int do_copy)
{
    int b = blockIdx.x / NCH, ch = blockIdx.x % NCH;
    int tid = threadIdx.x;
    int g = tid >> 5, l = tid & 31;

    __shared__ float sv[24];
    __shared__ int s_ia, s_ib, s_mask;

    if (t == 0) {
        if (tid == 0) { s_ia = 0; s_ib = 0; s_mask = 0xFF; }
        __syncthreads();
    } else {
        run_head(pprev, zeta, idxf, b, t, (ch == 0), tid, sv, &s_ia, &s_ib, &s_mask);
    }
    int ia = s_ia, ib = s_ib, mask = s_mask;

    // ---- fused gather copy for steps t-2, t-1 (ws path only) ----
    if (do_copy && t > 0) {
        const float4* apc4 = reinterpret_cast<const float4*>(apc);
        float4* out4 = reinterpret_cast<float4*>(gout);
        const float4* src0 = apc4 + (size_t)(ia * Bb + b) * CHW4;
        const float4* src1 = apc4 + (size_t)(ib * Bb + b) * CHW4;
        float4* dst0 = out4 + (size_t)((t - 1) * Bb + b) * CHW4;   // out[1+(t-2)]
        float4* dst1 = out4 + (size_t)(t * Bb + b) * CHW4;         // out[1+(t-1)]
        int cb = ch * 768 + tid;
#pragma unroll
        for (int i = 0; i < 3; ++i) {
            dst0[cb + i * 256] = src0[cb + i * 256];
            dst1[cb + i * 256] = src1[cb + i * 256];
        }
    }

    float pd = 0.f, pa = 0.f, pm = -1e30f;
    float accd[Kk], acca[Kk], accm[Kk];
#pragma unroll
    for (int c = 0; c < Kk; ++c) { accd[c] = 0.f; acca[c] = 0.f; accm[c] = -1e30f; }

    const size_t bHW = (size_t)b * HW;
    for (int i = 0; i < 8; ++i) {
        int px = ch * 1024 + (i * 32 + l) * 4;
        float4 sc0 = ld4(shp + (size_t)(0 * Bb + b) * HW + px);
        float4 sc1 = ld4(shp + (size_t)(1 * Bb + b) * HW + px);
        float4 sc2 = ld4(shp + (size_t)(2 * Bb + b) * HW + px);
        float4 sc3 = ld4(shp + (size_t)(3 * Bb + b) * HW + px);
        float4 sc4 = ld4(shp + (size_t)(4 * Bb + b) * HW + px);
        float4 sc5 = ld4(shp + (size_t)(5 * Bb + b) * HW + px);
        float4 sc6 = ld4(shp + (size_t)(6 * Bb + b) * HW + px);
        float4 sc7 = ld4(shp + (size_t)(7 * Bb + b) * HW + px);
        float4 sdg = ld4(sd  + (size_t)(g * Bb + b) * HW + px);
        float4 sg  = ld4(shp + (size_t)(g * Bb + b) * HW + px);   // L1 hit

        float4 P;
        if (t == 0) {
            P = make_float4(1.f, 1.f, 1.f, 1.f);
        } else {
            float4 p0 = make_float4(1.f, 1.f, 1.f, 1.f);
            if (t > 2) p0 = ld4(Pbuf + bHW + px);
            float4 sa = ld4(shp + (size_t)(ia * Bb + b) * HW + px);  // L1 hit
            float4 sb = ld4(shp + (size_t)(ib * Bb + b) * HW + px);  // L1 hit
            float4 p1;
            p1.x = p0.x * (1.f - sa.x * p0.x); p1.y = p0.y * (1.f - sa.y * p0.y);
            p1.z = p0.z * (1.f - sa.z * p0.z); p1.w = p0.w * (1.f - sa.w * p0.w);
            P.x = p1.x * (1.f - sb.x * p1.x); P.y = p1.y * (1.f - sb.y * p1.y);
            P.z = p1.z * (1.f - sb.z * p1.z); P.w = p1.w * (1.f - sb.w * p1.w);
            if ((t == 2 || t == 4) && g == 0) st4(Pbuf + bHW + px, P);
        }

#define SPEC_C(c, scv) if (mask & (1 << c)) { \
        float u = 1.f - scv * P_; float tt = m_ * u; \
        acca[c] += tt; accm[c] = fmaxf(accm[c], tt); accd[c] = fmaf(v_, u, accd[c]); }
#define DO_ELEM(e) { float P_ = P.e; float m_ = sg.e * P_; float v_ = sdg.e * P_; \
        pd += v_; pa += m_; pm = fmaxf(pm, m_); \
        SPEC_C(0, sc0.e) SPEC_C(1, sc1.e) SPEC_C(2, sc2.e) SPEC_C(3, sc3.e) \
        SPEC_C(4, sc4.e) SPEC_C(5, sc5.e) SPEC_C(6, sc6.e) SPEC_C(7, sc7.e) }
        DO_ELEM(x) DO_ELEM(y) DO_ELEM(z) DO_ELEM(w)
#undef DO_ELEM
#undef SPEC_C
    }

    // LDS reduce: per k-group (32 lanes), 27 values. stride 29 (coprime 32).
    __shared__ float ls[8][32][29];
    float* mine = ls[g][l];
#pragma unroll
    for (int c = 0; c < Kk; ++c) {
        mine[c * 3 + 0] = accd[c]; mine[c * 3 + 1] = acca[c]; mine[c * 3 + 2] = accm[c];
    }
    mine[24] = pd; mine[25] = pa; mine[26] = pm;
    __syncthreads();
    for (int st = 16; st > 0; st >>= 1) {
        if (l < st) {
            float* other = ls[g][l + st];
#pragma unroll
            for (int q = 0; q < QK; ++q)
                mine[q] = (q % 3 == 2) ? fmaxf(mine[q], other[q]) : (mine[q] + other[q]);
        }
        __syncthreads();
    }
    if (l == 0) {
#pragma unroll
        for (int q = 0; q < QK; ++q)
            pcur[(size_t)b * PARTN + (size_t)(g * QK + q) * NCH + ch] = mine[q];
    }
}

// ---------------------------------------------------------------------------
// Kernel 3: gather (4 float4/thread). img0=192, grid 1728 in the ws path
// (only t=6,7 remain; earlier slots were copied by the spec kernels);
// img0=0, grid 6912 in the fallback path (full r12 behaviour).
// ---------------------------------------------------------------------------
__global__ __launch_bounds__(256) void k_gather(
    const float* __restrict__ apc, const float* __restrict__ partials6,
    const float* __restrict__ zeta, float* idxf, float* __restrict__ out,
    int img0)
{
    int image = img0 + blockIdx.x / 27;    // 0..255 == t*32+b
    int chunk = blockIdx.x % 27;
    int t = image >> 5, b = image & 31;
    int tid = threadIdx.x;

    int s;
    if (t >= 6) {
        __shared__ float sv[24];
        __shared__ int s_ia, s_ib, s_mask;
        run_head(partials6, zeta, idxf, b, 8, (t == 6 && chunk == 0), tid,
                 sv, &s_ia, &s_ib, &s_mask);
        s = (t == 6) ? s_ia : s_ib;
    } else {
        s = clampK((int)idxf[t * Bb + b]);
    }

    const float4* src = reinterpret_cast<const float4*>(apc) + (size_t)(s * Bb + b) * CHW4;
    float4* dst = reinterpret_cast<float4*>(out) + (size_t)(image + Bb) * CHW4;
    int base = chunk * 1024 + tid;
    float4 r0 = src[base];
    float4 r1 = src[base + 256];
    float4 r2 = src[base + 512];
    float4 r3 = src[base + 768];
    dst[base]       = r0;
    dst[base + 256] = r1;
    dst[base + 512] = r2;
    dst[base + 768] = r3;
}

// ---------------------------------------------------------------------------
// Round 14: r12 base (217.6us, passed; r13's LDS staging reverted) + gather
// copies fused into spec kernels' memory slack (spec moves ~30MB in ~24us =
// 1.3 TB/s, far under the 6.3 wall; gather was 42us at the wall). spec2
// copies out[1,2], spec4 out[3,4], spec6 out[5,6]; final gather only t=6,7
// (1728 blocks). ws-path only (out[1..8] free early); fallback = exact r12.
// ---------------------------------------------------------------------------
extern "C" void kernel_launch(void* const* d_in, const int* in_sizes, int n_in,
                              void* d_out, int out_size, void* d_ws, size_t ws_size,
                              hipStream_t stream)
{
    const float *images = nullptr, *apc = nullptr, *shp = nullptr;
    const float *zeta = nullptr, *back = nullptr;
    for (int i = 0; i < n_in; ++i) {
        int s = in_sizes[i];
        if (s == 28311552)      apc  = (const float*)d_in[i];
        else if (s == 9437184)  shp  = (const float*)d_in[i];
        else if (s == 256)      zeta = (const float*)d_in[i];
        else if (s == 3538944) {
            if (!images) images = (const float*)d_in[i];
            else         back   = (const float*)d_in[i];
        }
    }
    if (!images || !apc || !shp || !zeta || !back) {   // fallback: dict order
        images = (const float*)d_in[0]; apc = (const float*)d_in[1];
        shp = (const float*)d_in[2]; zeta = (const float*)d_in[3];
        back = (const float*)d_in[4];
    }
    float* out = (float*)d_out;
    float* idxf = out + OUTMAIN;                       // 256-element tail

    int has_ws = (d_ws != nullptr && ws_size >= (size_t)48 * 1024 * 1024);
    // Scratch: sd(9437184) + Pbuf(1179648) + pA(248832) + pB(248832) = 44.5MB
    float* sd = has_ws ? (float*)d_ws
                       : (out + BCHW);   // alias into out[1..8], dead before gather
    float* Pbuf = sd + 9437184;
    float* pA   = Pbuf + 1179648;
    float* pB   = pA + 248832;

    k_pre_fused<<<1152, 256, 0, stream>>>(images, apc, shp, zeta, back, out, sd);
    k_spec<<<1152, 256, 0, stream>>>(shp, sd, Pbuf, idxf, zeta, pB, pA, apc, out, 0, has_ws);
    k_spec<<<1152, 256, 0, stream>>>(shp, sd, Pbuf, idxf, zeta, pA, pB, apc, out, 2, has_ws);
    k_spec<<<1152, 256, 0, stream>>>(shp, sd, Pbuf, idxf, zeta, pB, pA, apc, out, 4, has_ws);
    k_spec<<<1152, 256, 0, stream>>>(shp, sd, Pbuf, idxf, zeta, pA, pB, apc, out, 6, has_ws);
    if (has_ws) {
        k_gather<<<1728, 256, 0, stream>>>(apc, pB, zeta, idxf, out, 192);
    } else {
        k_gather<<<6912, 256, 0, stream>>>(apc, pB, zeta, idxf, out, 0);
    }
}

// Round 16
// 213.325 us; speedup vs baseline: 1.3627x; 1.0050x over previous
//
#include <hip/hip_runtime.h>
#include <math.h>

#define Kk 8
#define Bb 32
#define Cc 3
#define HW 36864          // 192*192
#define HW4 9216          // float4s per plane
#define CHW 110592        // 3*HW
#define CHW4 27648        // float4s per (k,b) image
#define BCHW 3538944      // B*C*HW
#define OUTMAIN 31850496  // 9*BCHW : index tail start in d_out (elements)
#define NCH 36            // chunks per batch (1024 px each)
#define QK 27             // per-k partial slots: spec[c][3] (24) + plain[3]
#define PARTN 7776        // 8*QK*NCH per batch
#define INVVAR 11.11111111111111f
#define EPSf 1e-5f

__device__ __forceinline__ int clampK(int v) { return v < 0 ? 0 : (v > Kk - 1 ? Kk - 1 : v); }
__device__ __forceinline__ float4 ld4(const float* p) { return *reinterpret_cast<const float4*>(p); }
__device__ __forceinline__ void st4(float* p, float4 v) { *reinterpret_cast<float4*>(p) = v; }

// ---------------------------------------------------------------------------
// Kernel 1: recon -> out[0] AND sd = shp*sum_c(apc-img)^2  (round-7 body).
// grid: 1152 x 256, 1 float4/thread.
// ---------------------------------------------------------------------------
__global__ __launch_bounds__(256) void k_pre_fused(
    const float* __restrict__ images, const float* __restrict__ apc,
    const float* __restrict__ shp, const float* __restrict__ zeta,
    const float* __restrict__ back, float* __restrict__ out,
    float* __restrict__ sd)
{
    int gid = blockIdx.x * 256 + threadIdx.x;
    int b = gid / HW4;
    int pix = (gid - b * HW4) * 4;

    float4 img[Cc], bk[Cc], rec[Cc];
#pragma unroll
    for (int c = 0; c < Cc; ++c) {
        img[c] = ld4(images + (size_t)(b * Cc + c) * HW + pix);
        bk[c]  = ld4(back   + (size_t)(b * Cc + c) * HW + pix);
        rec[c] = make_float4(0.f, 0.f, 0.f, 0.f);
    }
    float cum0 = 1.f, cum1 = 1.f, cum2 = 1.f, cum3 = 1.f;

#pragma unroll
    for (int k = 0; k < Kk; ++k) {
        float4 s = ld4(shp + (size_t)(k * Bb + b) * HW + pix);
        float z = zeta[k * Bb + b];
        float x0 = s.x * z, x1 = s.y * z, x2 = s.z * z, x3 = s.w * z;
        float g0 = x0 * cum0, g1 = x1 * cum1, g2 = x2 * cum2, g3 = x3 * cum3;
        float df0 = 0.f, df1 = 0.f, df2 = 0.f, df3 = 0.f;
#pragma unroll
        for (int c = 0; c < Cc; ++c) {
            float4 av = ld4(apc + ((size_t)(k * Bb + b) * Cc + c) * HW + pix);
            float d0 = av.x - img[c].x, d1 = av.y - img[c].y;
            float d2 = av.z - img[c].z, d3 = av.w - img[c].w;
            df0 += d0 * d0; df1 += d1 * d1; df2 += d2 * d2; df3 += d3 * d3;
            rec[c].x += g0 * av.x; rec[c].y += g1 * av.y;
            rec[c].z += g2 * av.z; rec[c].w += g3 * av.w;
        }
        st4(sd + (size_t)(k * Bb + b) * HW + pix,
            make_float4(s.x * df0, s.y * df1, s.z * df2, s.w * df3));
        cum0 *= (1.f - x0); cum1 *= (1.f - x1); cum2 *= (1.f - x2); cum3 *= (1.f - x3);
    }
#pragma unroll
    for (int c = 0; c < Cc; ++c) {
        st4(out + (size_t)(b * Cc + c) * HW + pix,
            make_float4(rec[c].x + cum0 * bk[c].x, rec[c].y + cum1 * bk[c].y,
                        rec[c].z + cum2 * bk[c].z, rec[c].w + cum3 * bk[c].w));
    }
}

// ---------------------------------------------------------------------------
// Head: resolve idx_{t-2} (plain) then idx_{t-1} (spec slice). Unchanged r12.
// ---------------------------------------------------------------------------
__device__ __forceinline__ void run_head(
    const float* __restrict__ pprev, const float* __restrict__ zeta,
    float* idxf, int b, int t, int write_idx, int tid,
    float* sv, int* s_ia, int* s_ib, int* s_mask)
{
    if (tid < 24) {
        int k = tid / 3, comp = tid - k * 3;
        float v = (comp == 2) ? -1e30f : 0.f;
        const float* src = pprev + (size_t)b * PARTN + (size_t)(k * QK + 24 + comp) * NCH;
        for (int j = 0; j < NCH; ++j) {
            float x = src[j];
            v = (comp == 2) ? fmaxf(v, x) : (v + x);
        }
        sv[tid] = v;
    }
    __syncthreads();
    if (tid == 0) {
        float best = -1e30f; int bi = 0;
        for (int k = 0; k < Kk; ++k) {
            float coef = 1.f;
            for (int j = 0; j < t - 2; ++j)
                if (clampK((int)idxf[j * Bb + b]) == k) coef = -1.f;
            float sc = coef * sv[3 * k + 2] * zeta[k * Bb + b] *
                       expf(-0.5f * INVVAR * sv[3 * k + 0] / (sv[3 * k + 1] + EPSf));
            if (sc > best) { best = sc; bi = k; }
        }
        *s_ia = bi;
    }
    __syncthreads();
    int ia = *s_ia;
    if (tid < 24) {
        int k = tid / 3, comp = tid - k * 3;
        float v = (comp == 2) ? -1e30f : 0.f;
        const float* src = pprev + (size_t)b * PARTN + (size_t)(k * QK + ia * 3 + comp) * NCH;
        for (int j = 0; j < NCH; ++j) {
            float x = src[j];
            v = (comp == 2) ? fmaxf(v, x) : (v + x);
        }
        sv[tid] = v;
    }
    __syncthreads();
    if (tid == 0) {
        float best = -1e30f; int bi = 0;
        for (int k = 0; k < Kk; ++k) {
            float coef = 1.f;
            for (int j = 0; j < t - 2; ++j)
                if (clampK((int)idxf[j * Bb + b]) == k) coef = -1.f;
            if (ia == k) coef = -1.f;
            float sc = coef * sv[3 * k + 2] * zeta[k * Bb + b] *
                       expf(-0.5f * INVVAR * sv[3 * k + 0] / (sv[3 * k + 1] + EPSf));
            if (sc > best) { best = sc; bi = k; }
        }
        *s_ib = bi;
        int mask = 0xFF;
        for (int j = 0; j < t - 2; ++j) mask &= ~(1 << clampK((int)idxf[j * Bb + b]));
        mask &= ~(1 << ia); mask &= ~(1 << bi);
        *s_mask = mask;
        if (write_idx) {
            idxf[(t - 2) * Bb + b] = (float)ia;
            idxf[(t - 1) * Bb + b] = (float)bi;
        }
    }
    __syncthreads();
}

// ---------------------------------------------------------------------------
// Kernel 2 (t=0,2,4,6): r14 body restructured to kill the Pbuf race that r15
// exposed: a separated P PHASE (all threads compute step-t P full-wave
// coalesced, store to Pbuf, __syncthreads) runs BEFORE the accumulate loop;
// the loop only READS Pbuf (block-private chunk, fresh by the barrier).
// Rotation is now safe: group g reads window (i+(g&1))&7 so the two
// half-waves of each wave hit adjacent 512B windows (1KB-unique loads).
// grid: 1152 x 256. partials: [b][k*27 + (c*3+comp | 24..26 plain)][ch]
// ---------------------------------------------------------------------------
__global__ __launch_bounds__(256, 4) void k_spec(
    const float* __restrict__ shp, const float* __restrict__ sd,
    float* __restrict__ Pbuf, float* idxf, const float* __restrict__ zeta,
    const float* __restrict__ pprev, float* __restrict__ pcur,
    const float* __restrict__ apc, float* __restrict__ gout,
    int t, int do_copy)
{
    int b = blockIdx.x / NCH, ch = blockIdx.x % NCH;
    int tid = threadIdx.x;
    int g = tid >> 5, l = tid & 31;

    __shared__ float sv[24];
    __shared__ int s_ia, s_ib, s_mask;

    if (t == 0) {
        if (tid == 0) { s_ia = 0; s_ib = 0; s_mask = 0xFF; }
        __syncthreads();
    } else {
        run_head(pprev, zeta, idxf, b, t, (ch == 0), tid, sv, &s_ia, &s_ib, &s_mask);
    }
    int ia = s_ia, ib = s_ib, mask = s_mask;

    // ---- fused gather copy for steps t-2, t-1 (ws path only) ----
    if (do_copy && t > 0) {
        const float4* apc4 = reinterpret_cast<const float4*>(apc);
        float4* out4 = reinterpret_cast<float4*>(gout);
        const float4* src0 = apc4 + (size_t)(ia * Bb + b) * CHW4;
        const float4* src1 = apc4 + (size_t)(ib * Bb + b) * CHW4;
        float4* dst0 = out4 + (size_t)((t - 1) * Bb + b) * CHW4;   // out[1+(t-2)]
        float4* dst1 = out4 + (size_t)(t * Bb + b) * CHW4;         // out[1+(t-1)]
        int cb = ch * 768 + tid;
#pragma unroll
        for (int i = 0; i < 3; ++i) {
            dst0[cb + i * 256] = src0[cb + i * 256];
            dst1[cb + i * 256] = src1[cb + i * 256];
        }
    }

    const size_t bHW = (size_t)b * HW;

    // ---- P PHASE (t>0): thread tid owns float4 #tid of the chunk ----
    if (t > 0) {
        int px = ch * 1024 + tid * 4;
        float4 p0 = make_float4(1.f, 1.f, 1.f, 1.f);
        if (t > 2) p0 = ld4(Pbuf + bHW + px);
        float4 sa = ld4(shp + (size_t)(ia * Bb + b) * HW + px);
        float4 sb = ld4(shp + (size_t)(ib * Bb + b) * HW + px);
        float4 p1, P;
        p1.x = p0.x * (1.f - sa.x * p0.x); p1.y = p0.y * (1.f - sa.y * p0.y);
        p1.z = p0.z * (1.f - sa.z * p0.z); p1.w = p0.w * (1.f - sa.w * p0.w);
        P.x = p1.x * (1.f - sb.x * p1.x); P.y = p1.y * (1.f - sb.y * p1.y);
        P.z = p1.z * (1.f - sb.z * p1.z); P.w = p1.w * (1.f - sb.w * p1.w);
        st4(Pbuf + bHW + px, P);
        __syncthreads();
    }

    // ---- accumulate: group g targets k=g; rotated windows ----
    float pd = 0.f, pa = 0.f, pm = -1e30f;
    float accd[Kk], acca[Kk], accm[Kk];
#pragma unroll
    for (int c = 0; c < Kk; ++c) { accd[c] = 0.f; acca[c] = 0.f; accm[c] = -1e30f; }

    const int rot = g & 1;                    // odd groups lead by one window
    for (int i = 0; i < 8; ++i) {
        int win = (i + rot) & 7;
        int px = ch * 1024 + (win * 32 + l) * 4;
        float4 sc0 = ld4(shp + (size_t)(0 * Bb + b) * HW + px);
        float4 sc1 = ld4(shp + (size_t)(1 * Bb + b) * HW + px);
        float4 sc2 = ld4(shp + (size_t)(2 * Bb + b) * HW + px);
        float4 sc3 = ld4(shp + (size_t)(3 * Bb + b) * HW + px);
        float4 sc4 = ld4(shp + (size_t)(4 * Bb + b) * HW + px);
        float4 sc5 = ld4(shp + (size_t)(5 * Bb + b) * HW + px);
        float4 sc6 = ld4(shp + (size_t)(6 * Bb + b) * HW + px);
        float4 sc7 = ld4(shp + (size_t)(7 * Bb + b) * HW + px);
        float4 sdg = ld4(sd  + (size_t)(g * Bb + b) * HW + px);
        float4 sg  = ld4(shp + (size_t)(g * Bb + b) * HW + px);   // L1 hit

        float4 P = make_float4(1.f, 1.f, 1.f, 1.f);
        if (t > 0) P = ld4(Pbuf + bHW + px);    // fresh by the barrier; L1-hot

#define SPEC_C(c, scv) if (mask & (1 << c)) { \
        float u = 1.f - scv * P_; float tt = m_ * u; \
        acca[c] += tt; accm[c] = fmaxf(accm[c], tt); accd[c] = fmaf(v_, u, accd[c]); }
#define DO_ELEM(e) { float P_ = P.e; float m_ = sg.e * P_; float v_ = sdg.e * P_; \
        pd += v_; pa += m_; pm = fmaxf(pm, m_); \
        SPEC_C(0, sc0.e) SPEC_C(1, sc1.e) SPEC_C(2, sc2.e) SPEC_C(3, sc3.e) \
        SPEC_C(4, sc4.e) SPEC_C(5, sc5.e) SPEC_C(6, sc6.e) SPEC_C(7, sc7.e) }
        DO_ELEM(x) DO_ELEM(y) DO_ELEM(z) DO_ELEM(w)
#undef DO_ELEM
#undef SPEC_C
    }

    // LDS reduce: per k-group (32 lanes), 27 values. stride 29 (coprime 32).
    __shared__ float ls[8][32][29];
    float* mine = ls[g][l];
#pragma unroll
    for (int c = 0; c < Kk; ++c) {
        mine[c * 3 + 0] = accd[c]; mine[c * 3 + 1] = acca[c]; mine[c * 3 + 2] = accm[c];
    }
    mine[24] = pd; mine[25] = pa; mine[26] = pm;
    __syncthreads();
    for (int st = 16; st > 0; st >>= 1) {
        if (l < st) {
            float* other = ls[g][l + st];
#pragma unroll
            for (int q = 0; q < QK; ++q)
                mine[q] = (q % 3 == 2) ? fmaxf(mine[q], other[q]) : (mine[q] + other[q]);
        }
        __syncthreads();
    }
    if (l == 0) {
#pragma unroll
        for (int q = 0; q < QK; ++q)
            pcur[(size_t)b * PARTN + (size_t)(g * QK + q) * NCH + ch] = mine[q];
    }
}

// ---------------------------------------------------------------------------
// Kernel 3: gather (4 float4/thread). img0=192, grid 1728 in the ws path
// (only t=6,7 remain); img0=0, grid 6912 in the fallback path.
// ---------------------------------------------------------------------------
__global__ __launch_bounds__(256) void k_gather(
    const float* __restrict__ apc, const float* __restrict__ partials6,
    const float* __restrict__ zeta, float* idxf, float* __restrict__ out,
    int img0)
{
    int image = img0 + blockIdx.x / 27;    // 0..255 == t*32+b
    int chunk = blockIdx.x % 27;
    int t = image >> 5, b = image & 31;
    int tid = threadIdx.x;

    int s;
    if (t >= 6) {
        __shared__ float sv[24];
        __shared__ int s_ia, s_ib, s_mask;
        run_head(partials6, zeta, idxf, b, 8, (t == 6 && chunk == 0), tid,
                 sv, &s_ia, &s_ib, &s_mask);
        s = (t == 6) ? s_ia : s_ib;
    } else {
        s = clampK((int)idxf[t * Bb + b]);
    }

    const float4* src = reinterpret_cast<const float4*>(apc) + (size_t)(s * Bb + b) * CHW4;
    float4* dst = reinterpret_cast<float4*>(out) + (size_t)(image + Bb) * CHW4;
    int base = chunk * 1024 + tid;
    float4 r0 = src[base];
    float4 r1 = src[base + 256];
    float4 r2 = src[base + 512];
    float4 r3 = src[base + 768];
    dst[base]       = r0;
    dst[base + 256] = r1;
    dst[base + 512] = r2;
    dst[base + 768] = r3;
}

// ---------------------------------------------------------------------------
// Round 16: r15's rotation exposed a latent Pbuf read/write race (g0 stored
// new P mid-loop while other groups loaded old P from the same addresses;
// rotation turned the lucky lockstep into a guaranteed stale read for odd
// groups at window 0). Fix: separated P phase (compute+store before the
// loop, barrier, loop only reads). Rotation retained. Else identical to r14.
// ---------------------------------------------------------------------------
extern "C" void kernel_launch(void* const* d_in, const int* in_sizes, int n_in,
                              void* d_out, int out_size, void* d_ws, size_t ws_size,
                              hipStream_t stream)
{
    const float *images = nullptr, *apc = nullptr, *shp = nullptr;
    const float *zeta = nullptr, *back = nullptr;
    for (int i = 0; i < n_in; ++i) {
        int s = in_sizes[i];
        if (s == 28311552)      apc  = (const float*)d_in[i];
        else if (s == 9437184)  shp  = (const float*)d_in[i];
        else if (s == 256)      zeta = (const float*)d_in[i];
        else if (s == 3538944) {
            if (!images) images = (const float*)d_in[i];
            else         back   = (const float*)d_in[i];
        }
    }
    if (!images || !apc || !shp || !zeta || !back) {   // fallback: dict order
        images = (const float*)d_in[0]; apc = (const float*)d_in[1];
        shp = (const float*)d_in[2]; zeta = (const float*)d_in[3];
        back = (const float*)d_in[4];
    }
    float* out = (float*)d_out;
    float* idxf = out + OUTMAIN;                       // 256-element tail

    int has_ws = (d_ws != nullptr && ws_size >= (size_t)48 * 1024 * 1024);
    // Scratch: sd(9437184) + Pbuf(1179648) + pA(248832) + pB(248832) = 44.5MB
    float* sd = has_ws ? (float*)d_ws
                       : (out + BCHW);   // alias into out[1..8], dead before gather
    float* Pbuf = sd + 9437184;
    float* pA   = Pbuf + 1179648;
    float* pB   = pA + 248832;

    k_pre_fused<<<1152, 256, 0, stream>>>(images, apc, shp, zeta, back, out, sd);
    k_spec<<<1152, 256, 0, stream>>>(shp, sd, Pbuf, idxf, zeta, pB, pA, apc, out, 0, has_ws);
    k_spec<<<1152, 256, 0, stream>>>(shp, sd, Pbuf, idxf, zeta, pA, pB, apc, out, 2, has_ws);
    k_spec<<<1152, 256, 0, stream>>>(shp, sd, Pbuf, idxf, zeta, pB, pA, apc, out, 4, has_ws);
    k_spec<<<1152, 256, 0, stream>>>(shp, sd, Pbuf, idxf, zeta, pA, pB, apc, out, 6, has_ws);
    if (has_ws) {
        k_gather<<<1728, 256, 0, stream>>>(apc, pB, zeta, idxf, out, 192);
    } else {
        k_gather<<<6912, 256, 0, stream>>>(apc, pB, zeta, idxf, out, 0);
    }
}